// Round 14
// baseline (1505.994 us; speedup 1.0000x reference)
//
#include <hip/hip_runtime.h>
#include <stdint.h>

typedef float f32x4 __attribute__((ext_vector_type(4)));
typedef _Float16 h16x8 __attribute__((ext_vector_type(8)));
typedef _Float16 h16;
typedef unsigned short u16;

// ---------------- prep kernels ----------------

// LDS-tiled transpose(+optional split3): out (Cn x ostride) from in (Ck x Cn) fp32
__global__ void k_split_t(const float* __restrict__ in, h16* __restrict__ out,
                          int Cn, int Ck, int ostride, int doSplit) {
  __shared__ float t[32][33];
  int n0 = blockIdx.x * 32, k0 = blockIdx.y * 32;
  int tx = threadIdx.x, ty = threadIdx.y;
#pragma unroll
  for (int i = 0; i < 4; ++i)
    t[ty + i * 8][tx] = in[(size_t)(k0 + ty + i * 8) * Cn + n0 + tx];
  __syncthreads();
#pragma unroll
  for (int i = 0; i < 4; ++i) {
    int n = n0 + ty + i * 8, k = k0 + tx;
    float v = t[tx][ty + i * 8];
    h16 h = (h16)v;
    size_t base = (size_t)n * ostride + k;
    out[base] = h;
    if (doSplit) {
      out[base + Ck] = h;
      out[base + 2 * Ck] = (h16)(v - (float)h);
    }
  }
}

// Xcat chunk (CH x 704): [Xh | Xl] for rows [r0, r0+CH)
__global__ void k_xcat(const float* __restrict__ qe, const float* __restrict__ probs,
                       const float* __restrict__ bbox, h16* __restrict__ x, int r0, int n) {
  int i = blockIdx.x * 256 + threadIdx.x;
  if (i >= n) return;
  int rl = i / 352, k = i - rl * 352;
  int R = r0 + rl;
  int nn = R & 1023;
  float v;
  if (k < 256)      v = qe[nn * 256 + k];
  else if (k < 348) v = probs[(size_t)R * 92 + (k - 256)];
  else              v = bbox[(size_t)R * 4 + (k - 348)];
  h16 h = (h16)v;
  h16 l = (h16)(v - (float)h);
  size_t base = (size_t)rl * 704;
  x[base + k] = h; x[base + 352 + k] = l;
}

// xw1f = node_emb @ conv1_w  in fp32 (1024 x 512)
__global__ void k_xw1(const float* __restrict__ ne, const float* __restrict__ c1w,
                      float* __restrict__ xw1f) {
  int r = blockIdx.x >> 1;
  int d = (blockIdx.x & 1) * 256 + threadIdx.x;
  float s = 0.0f;
  for (int k = 0; k < 256; ++k) s += ne[r * 256 + k] * c1w[k * 512 + d];
  xw1f[r * 512 + d] = s;
}

// ---------------- 8-phase 256x256 fp16 MFMA GEMM (BK=64, swizzled LDS, counted vmcnt) ----
// A: (M x AK) row-major fp16; logical K may exceed AK: tiles with base >= AK wrap to base-AK.
// B: (N x K) row-major fp16 (transposed operand). M%256==0, N%256==0, K%64==0.
// MODE 2: fp32 out = acc + bias
// MODE 3: relu(acc+bias) split2 fp16 out (row stride 2N): [c]=hi, [N+c]=lo
// MODE 4: fp16 out row-major = acc*rscale[r] + bias

template<int MODE>
__global__ __launch_bounds__(512, 2)
void k_gemm8(const h16* __restrict__ A, const h16* __restrict__ B, void* __restrict__ Cptr,
             const float* __restrict__ bias, const float* __restrict__ rscale,
             int M, int N, int K, int AK) {
  __shared__ __align__(16) char lds[131072];   // A: [2][256 rows][128B] @0 ; B same @65536
  const int tid = threadIdx.x;
  const int lane = tid & 63, wid = tid >> 6;
  const int wr = wid >> 2, wc = wid & 3;       // 2 x 4 waves, wave tile 128x64

  const int gx = N >> 8;
  const int nwg = gridDim.x, wg = blockIdx.x;
  const int q8 = nwg >> 3, r8 = nwg & 7, xcd = wg & 7, lo = wg >> 3;
  const int swz = (xcd < r8 ? xcd * (q8 + 1) : r8 * (q8 + 1) + (xcd - r8) * q8) + lo;
  const int bx = swz % gx, by = swz / gx;

  const int nt = K >> 6;
  const int srow = tid >> 3, s8 = tid & 7;

  char* ldsA = (char*)lds;
  char* ldsB = (char*)lds + 65536;

  auto stage = [&](const h16* __restrict__ Mat, int rowStride, int tileRowBase,
                   char* ldsBase, int buf, int half, int kbase) {
#pragma unroll
    for (int j = 0; j < 2; ++j) {
      int rl = half * 128 + srow + j * 64;
      int gcol = kbase + ((s8 ^ (rl & 7)) << 3);
      const char* src = (const char*)(Mat + (size_t)(tileRowBase + rl) * rowStride + gcol);
      char* dst = ldsBase + buf * 32768 + half * 16384 + j * 8192 + tid * 16;
      __builtin_amdgcn_global_load_lds((const __attribute__((address_space(1))) void*)src,
                                       (__attribute__((address_space(3))) void*)dst, 16, 0, 0);
    }
  };

  f32x4 acc[8][4] = {};
  h16x8 bfr[4][2];

  auto rdA = [&](int buf, int mf, int ks) -> h16x8 {
    int row = wr * 128 + mf * 16 + (lane & 15);
    int cb = ((ks << 6) + ((lane >> 4) << 4)) ^ ((row & 7) << 4);
    return *(const h16x8*)(ldsA + buf * 32768 + row * 128 + cb);
  };
  auto rdB = [&](int buf, int nf, int ks) -> h16x8 {
    int row = wc * 64 + nf * 16 + (lane & 15);
    int cb = ((ks << 6) + ((lane >> 4) << 4)) ^ ((row & 7) << 4);
    return *(const h16x8*)(ldsB + buf * 32768 + row * 128 + cb);
  };

#define BARRIER() do { asm volatile("" ::: "memory"); \
  __builtin_amdgcn_s_barrier(); asm volatile("" ::: "memory"); } while (0)

#define MFMA16(q, af)                                                          \
  __builtin_amdgcn_s_setprio(1);                                               \
  _Pragma("unroll") for (int m2 = 0; m2 < 2; ++m2)                             \
  _Pragma("unroll") for (int nf = 0; nf < 4; ++nf)                             \
  _Pragma("unroll") for (int ks = 0; ks < 2; ++ks)                             \
    acc[(q) * 2 + m2][nf] = __builtin_amdgcn_mfma_f32_16x16x32_f16(            \
        af[m2][ks], bfr[nf][ks], acc[(q) * 2 + m2][nf], 0, 0, 0);              \
  __builtin_amdgcn_s_setprio(0);

  const int aRow = by * 256, bRow = bx * 256;

  stage(A, AK, aRow, ldsA, 0, 0, 0);
  stage(A, AK, aRow, ldsA, 0, 1, 0);
  stage(B, K, bRow, ldsB, 0, 0, 0);
  stage(B, K, bRow, ldsB, 0, 1, 0);
  stage(B, K, bRow, ldsB, 1, 0, 64);
  stage(B, K, bRow, ldsB, 1, 1, 64);
  asm volatile("s_waitcnt vmcnt(4)" ::: "memory");
  BARRIER();

  for (int T = 0; T < nt; ++T) {
    const int p = T & 1;
    const int tkA = (T + 1) << 6;
    const int aA = (tkA < AK) ? tkA : tkA - AK;
    const int tkB = (T + 2) << 6;
    const bool sA = (T + 1) < nt, sB = (T + 2) < nt;

    {
#pragma unroll
      for (int nf = 0; nf < 4; ++nf)
#pragma unroll
        for (int ks = 0; ks < 2; ++ks) bfr[nf][ks] = rdB(p, nf, ks);
      h16x8 af[2][2];
#pragma unroll
      for (int m2 = 0; m2 < 2; ++m2)
#pragma unroll
        for (int ks = 0; ks < 2; ++ks) af[m2][ks] = rdA(p, m2, ks);
      if (sA) stage(A, AK, aRow, ldsA, p ^ 1, 0, aA);
      BARRIER();
      MFMA16(0, af)
      BARRIER();
    }
    {
      h16x8 af[2][2];
#pragma unroll
      for (int m2 = 0; m2 < 2; ++m2)
#pragma unroll
        for (int ks = 0; ks < 2; ++ks) af[m2][ks] = rdA(p, 2 + m2, ks);
      if (sA) stage(A, AK, aRow, ldsA, p ^ 1, 1, aA);
      BARRIER();
      MFMA16(1, af)
      BARRIER();
    }
    {
      h16x8 af[2][2];
#pragma unroll
      for (int m2 = 0; m2 < 2; ++m2)
#pragma unroll
        for (int ks = 0; ks < 2; ++ks) af[m2][ks] = rdA(p, 4 + m2, ks);
      if (sB) stage(B, K, bRow, ldsB, p, 0, tkB);
      BARRIER();
      MFMA16(2, af)
      BARRIER();
    }
    {
      h16x8 af[2][2];
#pragma unroll
      for (int m2 = 0; m2 < 2; ++m2)
#pragma unroll
        for (int ks = 0; ks < 2; ++ks) af[m2][ks] = rdA(p, 6 + m2, ks);
      if (sB) stage(B, K, bRow, ldsB, p, 1, tkB);
      BARRIER();
      MFMA16(3, af)
      if (sB) { asm volatile("s_waitcnt vmcnt(4)" ::: "memory"); }
      else    { asm volatile("s_waitcnt vmcnt(0)" ::: "memory"); }
      BARRIER();
    }
  }

  const int tM = by * 256 + wr * 128, tN = bx * 256 + wc * 64;
#pragma unroll
  for (int mf = 0; mf < 8; ++mf) {
#pragma unroll
    for (int nf = 0; nf < 4; ++nf) {
      int c = tN + nf * 16 + (lane & 15);
      float bvl = bias[c];
#pragma unroll
      for (int i = 0; i < 4; ++i) {
        int r = tM + mf * 16 + (lane >> 4) * 4 + i;
        float v = acc[mf][nf][i];
        if (MODE == 4) v = v * rscale[r] + bvl;
        else v += bvl;
        if (MODE == 2) {
          ((float*)Cptr)[(size_t)r * N + c] = v;
        } else if (MODE == 4) {
          ((h16*)Cptr)[(size_t)r * N + c] = (h16)v;
        } else {                       // MODE 3: relu + split2, row stride 2N
          v = fmaxf(v, 0.0f);
          h16 h = (h16)v;
          h16 l = (h16)(v - (float)h);
          size_t o = (size_t)r * (2 * N) + c;
          ((h16*)Cptr)[o] = h;
          ((h16*)Cptr)[o + N] = l;
        }
      }
    }
  }
#undef BARRIER
#undef MFMA16
}

// ---------------- legacy 128x128 GEMM (GCN tail; 16KB LDS, multi-wg/CU) ----------------
// MODE 1: fp16 out, per-1024-row-batch transposed; MODE 2: fp32 out
// MODE 4: fp16 out row-major (rscale+bias supported in all modes)

template<int MODE, int RELU>
__global__ __launch_bounds__(256)
void k_gemm(const h16* __restrict__ A, const h16* __restrict__ B, void* __restrict__ Cptr,
            const float* __restrict__ bias, const float* __restrict__ rscale,
            int M, int N, int K, int AK, int gx,
            long long sA, long long sB, long long sC) {
  __shared__ __align__(16) h16 As[128 * 32];
  __shared__ __align__(16) h16 Bs[128 * 32];
  const int tid = threadIdx.x;
  const int wid = tid >> 6, lane = tid & 63;
  const int wr = wid >> 1, wc = wid & 1;
  const int bz = blockIdx.y;

  const int nwg = gridDim.x, wg = blockIdx.x;
  const int q = nwg >> 3, r8 = nwg & 7, xcd = wg & 7, lo = wg >> 3;
  const int swz = (xcd < r8 ? xcd * (q + 1) : r8 * (q + 1) + (xcd - r8) * q) + lo;
  const int bx = swz % gx, by = swz / gx;

  const char* gA = (const char*)(A + (size_t)bz * sA + (size_t)by * 128 * AK +
                                 (size_t)(tid >> 2) * AK) + (tid & 3) * 16;
  const char* gB = (const char*)(B + (size_t)bz * sB + (size_t)bx * 128 * K +
                                 (size_t)(tid >> 2) * K) + (tid & 3) * 16;
  char* lAs = (char*)As + wid * 1024;
  char* lBs = (char*)Bs + wid * 1024;
  const long long rowStepA = (long long)64 * AK * 2;
  const long long rowStepB = (long long)64 * K * 2;

  f32x4 acc[4][4] = {};
  const int aoff = (wr * 64 + (lane & 15)) * 32 + (lane >> 4) * 8;
  const int boff = (wc * 64 + (lane & 15)) * 32 + (lane >> 4) * 8;

  for (int kt = 0; kt < K; kt += 32) {
    const int akt = (kt < AK) ? kt : kt - AK;
    __syncthreads();
#pragma unroll
    for (int j = 0; j < 2; ++j) {
      __builtin_amdgcn_global_load_lds(
          (const __attribute__((address_space(1))) void*)(gA + j * rowStepA + (size_t)akt * 2),
          (__attribute__((address_space(3))) void*)(lAs + j * 4096), 16, 0, 0);
      __builtin_amdgcn_global_load_lds(
          (const __attribute__((address_space(1))) void*)(gB + j * rowStepB + (size_t)kt * 2),
          (__attribute__((address_space(3))) void*)(lBs + j * 4096), 16, 0, 0);
    }
    asm volatile("s_waitcnt vmcnt(0)" ::: "memory");
    __syncthreads();

    h16x8 af[4], bv[4];
#pragma unroll
    for (int m = 0; m < 4; ++m) af[m] = *(const h16x8*)(As + aoff + m * 512);
#pragma unroll
    for (int n = 0; n < 4; ++n) bv[n] = *(const h16x8*)(Bs + boff + n * 512);
#pragma unroll
    for (int m = 0; m < 4; ++m)
#pragma unroll
      for (int n = 0; n < 4; ++n)
        acc[m][n] = __builtin_amdgcn_mfma_f32_16x16x32_f16(af[m], bv[n], acc[m][n], 0, 0, 0);
  }

  const int tM = by * 128 + wr * 64, tN = bx * 128 + wc * 64;
#pragma unroll
  for (int m = 0; m < 4; ++m) {
#pragma unroll
    for (int n = 0; n < 4; ++n) {
      int c = tN + n * 16 + (lane & 15);
      float bvl = bias ? bias[c] : 0.0f;
#pragma unroll
      for (int i = 0; i < 4; ++i) {
        int r = tM + m * 16 + (lane >> 4) * 4 + i;
        float v = acc[m][n][i];
        if (rscale) v *= rscale[bz * 1024 + r];
        v += bvl;
        if (RELU) v = fmaxf(v, 0.0f);
        if (MODE == 1) {
          size_t o = ((size_t)(r >> 10) * N + c) * 1024 + (r & 1023);
          ((h16*)Cptr)[o] = (h16)v;
        } else if (MODE == 2) {
          size_t o = (size_t)bz * sC + (size_t)r * N + c;
          ((float*)Cptr)[o] = v;
        } else if (MODE == 4) {
          size_t o = (size_t)bz * sC + (size_t)r * N + c;
          ((h16*)Cptr)[o] = (h16)v;
        }
      }
    }
  }
}

// ---------------- top-k via 4-level (full 32-bit) radix select, one wave per row ----
// Fuses degree accumulation (deg pre-initialized to 1.0).

__global__ void k_topk(const float* __restrict__ adj, float* __restrict__ vals,
                       u16* __restrict__ idxo, float* __restrict__ deg, int r0) {
  __shared__ unsigned binsAll[4][256];
  const int wv = threadIdx.x >> 6, lane = threadIdx.x & 63;
  unsigned* bins = binsAll[wv];
  const int rl = blockIdx.x * 4 + wv;

  float v[16]; unsigned key[16];
  const float4* rp = (const float4*)(adj + (size_t)rl * 1024 + lane * 16);
#pragma unroll
  for (int q = 0; q < 4; ++q) {
    float4 t = rp[q];
    v[4 * q] = t.x; v[4 * q + 1] = t.y; v[4 * q + 2] = t.z; v[4 * q + 3] = t.w;
  }
#pragma unroll
  for (int j = 0; j < 16; ++j) {
    unsigned b = __float_as_uint(v[j]);
    key[j] = b ^ (unsigned)(((int)b >> 31) | (int)0x80000000);
  }

  unsigned pfx = 0; int need = 32;
#pragma unroll
  for (int lvl = 0; lvl < 4; ++lvl) {
    const int shift = 24 - lvl * 8;
    bins[lane] = 0; bins[lane + 64] = 0; bins[lane + 128] = 0; bins[lane + 192] = 0;
    __syncthreads();
#pragma unroll
    for (int j = 0; j < 16; ++j) {
      bool cand = (lvl == 0) || ((key[j] >> (shift + 8)) == pfx);
      if (cand) atomicAdd(&bins[(key[j] >> shift) & 255u], 1u);
    }
    __syncthreads();
    int c0 = (int)bins[lane * 4 + 0], c1 = (int)bins[lane * 4 + 1],
        c2 = (int)bins[lane * 4 + 2], c3 = (int)bins[lane * 4 + 3];
    int s = c0 + c1 + c2 + c3;
    int inc = s;
#pragma unroll
    for (int off = 1; off < 64; off <<= 1) {
      int t = __shfl_down(inc, off);
      if (lane + off < 64) inc += t;
    }
    int gt3 = inc - s;
    int gt2 = gt3 + c3, gt1 = gt2 + c2, gt0 = gt1 + c1;
    int tloc = -1, gtsel = 0;
    if (gt3 < need && gt3 + c3 >= need) { tloc = lane * 4 + 3; gtsel = gt3; }
    if (gt2 < need && gt2 + c2 >= need) { tloc = lane * 4 + 2; gtsel = gt2; }
    if (gt1 < need && gt1 + c1 >= need) { tloc = lane * 4 + 1; gtsel = gt1; }
    if (gt0 < need && gt0 + c0 >= need) { tloc = lane * 4 + 0; gtsel = gt0; }
    unsigned long long bal = __ballot(tloc >= 0);
    int src = __ffsll(bal) - 1;
    int t   = __shfl(tloc, src);
    int gtv = __shfl(gtsel, src);
    pfx = (pfx << 8) | (unsigned)t;
    need -= gtv;
    __syncthreads();
  }

  // pfx is now the full 32-bit key of the 32nd element (the threshold key).
  unsigned sureMask = 0, tieMask = 0;
#pragma unroll
  for (int j = 0; j < 16; ++j) {
    if (key[j] > pfx) sureMask |= (1u << j);
    else if (key[j] == pfx) tieMask |= (1u << j);
  }
  int cs = __popc(sureMask), ct = __popc(tieMask);
  int incS = cs, incT = ct;
#pragma unroll
  for (int off = 1; off < 64; off <<= 1) {
    int a = __shfl_up(incS, off);
    int b2 = __shfl_up(incT, off);
    if (lane >= off) { incS += a; incT += b2; }
  }
  int baseS = incS - cs, baseT = incT - ct;
  int totalS = __shfl(incS, 63);
  size_t obase = ((size_t)(r0 + rl)) * 32;
  int degb = ((r0 + rl) >> 10) << 10;      // batch * 1024
  int o = baseS;
#pragma unroll
  for (int j = 0; j < 16; ++j)
    if (sureMask & (1u << j)) {
      vals[obase + o] = v[j];
      idxo[obase + o] = (u16)(lane * 16 + j);
      atomicAdd(&deg[degb + lane * 16 + j], v[j]);
      ++o;
    }
  int o2 = totalS + baseT;
#pragma unroll
  for (int j = 0; j < 16; ++j)
    if (tieMask & (1u << j)) {
      if (o2 < 32) {
        vals[obase + o2] = v[j];
        idxo[obase + o2] = (u16)(lane * 16 + j);
        atomicAdd(&deg[degb + lane * 16 + j], v[j]);
      }
      ++o2;
    }
}

// ---------------- degree / dinv / W build (dr folded into W columns) ----------------

__global__ void k_deg_init(float* deg) {
  int i = blockIdx.x * 256 + threadIdx.x;
  if (i < 65536) deg[i] = 1.0f;
}

__global__ void k_dinv(const float* __restrict__ deg, float* __restrict__ dinv) {
  int i = blockIdx.x * 256 + threadIdx.x;
  if (i >= 65536) return;
  float d = deg[i];
  float r = 1.0f / sqrtf(d);
  if (isinf(r)) r = 0.0f;
  dinv[i] = r;
}

__global__ void k_self(const float* __restrict__ dinv, h16* __restrict__ Wd, int g) {
  int i = blockIdx.x * 256 + threadIdx.x;
  if (i >= 16384) return;
  int bl = i >> 10, c = i & 1023;
  Wd[((size_t)bl << 20) + (size_t)c * 1024 + c] = (h16)dinv[g * 16384 + i];
}

__global__ void k_edge(const float* __restrict__ vals, const u16* __restrict__ idxo,
                       const float* __restrict__ dinv, h16* __restrict__ Wd, int g) {
  int e = blockIdx.x * 256 + threadIdx.x;
  if (e >= 524288) return;
  int bl = e >> 15;
  int r = (e >> 5) & 1023;
  size_t E = (size_t)g * 524288 + e;
  int c = (int)idxo[E];
  float w = vals[E] * dinv[g * 16384 + (bl << 10) + r];
  size_t o = ((size_t)bl << 20) + (size_t)c * 1024 + r;
  Wd[o] = (h16)((float)Wd[o] + w);
}

// ---------------- batchnorm (fp16 h1, in-place apply), two-stage ----------------

__global__ void k_bnpart(const h16* __restrict__ h1, float2* __restrict__ part) {
  int b = blockIdx.x, seg = blockIdx.y, d = threadIdx.x;
  size_t base = ((size_t)(b * 1024 + seg * 128)) * 512 + d;
  float s = 0.0f, ss = 0.0f;
  for (int n = 0; n < 128; ++n) {
    float h = (float)h1[base + (size_t)n * 512];
    s += h; ss += h * h;
  }
  part[(size_t)(b * 8 + seg) * 512 + d] = make_float2(s, ss);
}

__global__ void k_bnfin(const float2* __restrict__ part, float* __restrict__ mu,
                        float* __restrict__ rstd) {
  int i = blockIdx.x * 256 + threadIdx.x;
  if (i >= 8192) return;
  int b = i >> 9, d = i & 511;
  float s = 0.0f, ss = 0.0f;
  for (int seg = 0; seg < 8; ++seg) {
    float2 t = part[(size_t)(b * 8 + seg) * 512 + d];
    s += t.x; ss += t.y;
  }
  float m = s * (1.0f / 1024.0f);
  float var = ss * (1.0f / 1024.0f) - m * m;
  mu[b * 512 + d] = m;
  rstd[b * 512 + d] = 1.0f / sqrtf(var + 1e-5f);
}

// vectorized: 8 fp16 per thread (d-contiguous)
__global__ void k_bnapply(h16* __restrict__ h1, const float* __restrict__ mu,
                          const float* __restrict__ rstd, const float* __restrict__ gamma,
                          const float* __restrict__ beta) {
  int i = blockIdx.x * 256 + threadIdx.x;       // 16*1024*512/8 = 1,048,576 threads
  if (i >= 1048576) return;
  int i8 = i * 8;
  int d0 = i8 & 511;
  int b = i8 >> 19;
  h16x8 hv = *(const h16x8*)(h1 + i8);
  h16x8 ov;
#pragma unroll
  for (int j = 0; j < 8; ++j) {
    int d = d0 + j;
    float y = ((float)hv[j] - mu[b * 512 + d]) * rstd[b * 512 + d] * gamma[d] + beta[d];
    ov[j] = (h16)fmaxf(y, 0.0f);
  }
  *(h16x8*)(h1 + i8) = ov;
}

// ---------------- launch ----------------

extern "C" void kernel_launch(void* const* d_in, const int* in_sizes, int n_in,
                              void* d_out, int out_size, void* d_ws, size_t ws_size,
                              hipStream_t stream) {
  const float* probs = (const float*)d_in[0];
  const float* bbox  = (const float*)d_in[1];
  const float* qe    = (const float*)d_in[2];
  const float* ne    = (const float*)d_in[3];
  const float* w1    = (const float*)d_in[4];
  const float* b1    = (const float*)d_in[5];
  const float* w2    = (const float*)d_in[6];
  const float* b2    = (const float*)d_in[7];
  const float* c1w   = (const float*)d_in[8];
  const float* c1b   = (const float*)d_in[9];
  const float* c2w   = (const float*)d_in[10];
  const float* c2b   = (const float*)d_in[11];
  const float* gamma = (const float*)d_in[12];
  const float* beta  = (const float*)d_in[13];

  if (ws_size < 82444288ULL) return;               // minimum layout
  const bool big = ws_size >= 115998720ULL;        // 16K-row MLP chunks if room
  const int CH = big ? 16384 : 8192;
  const int NCH = 65536 / CH;

  char* p = (char*)d_ws;
  h16* W1cat = (h16*)p; p += (size_t)1024 * 1088 * 2;   //  K padded to 1088
  h16* W2cat = (h16*)p; p += (size_t)1024 * 3072 * 2;
  h16* c2wt  = (h16*)p; p += (size_t)256 * 512 * 2;
  float* xw1f = (float*)p; p += (size_t)1024 * 512 * 4;
  h16*  xw1t = (h16*)p;  p += (size_t)512 * 1024 * 2;
  float* vals = (float*)p; p += (size_t)2097152 * 4;
  u16*   idxo = (u16*)p;   p += (size_t)2097152 * 2;
  float* deg  = (float*)p; p += (size_t)65536 * 4;
  float* dinv = (float*)p; p += (size_t)65536 * 4;
  float* mu   = (float*)p; p += (size_t)64 * 512 * 4;
  float* rstd = (float*)p; p += (size_t)64 * 512 * 4;
  float2* bnp = (float2*)p; p += (size_t)16 * 8 * 512 * 8;
  char* R1 = p;
  // MLP phase: Xcat (CH x 704 fp16) | Hcat2 (CH x 2048 fp16)
  h16* Xcat  = (h16*)R1;
  h16* Hcat2 = (h16*)(R1 + (size_t)CH * 704 * 2);
  // GCN phase: Wd(32MB) | h1(16MB) | xw2t(8MB)
  h16* Wd   = (h16*)R1;
  h16* h1   = (h16*)(R1 + 33554432);
  h16* xw2t = (h16*)(R1 + 50331648);
  float* adjf = (float*)d_out;                     // CH x 1024 fp32 chunk

  // ---- weight prep ----
  hipMemsetAsync(W1cat, 0, (size_t)1024 * 1088 * 2, stream);
  k_split_t<<<dim3(32, 11), dim3(32, 8), 0, stream>>>(w1, W1cat, 1024, 352, 1088, 1);
  k_split_t<<<dim3(32, 32), dim3(32, 8), 0, stream>>>(w2, W2cat, 1024, 1024, 3072, 1);
  k_split_t<<<dim3(8, 16), dim3(32, 8), 0, stream>>>(c2w, c2wt, 256, 512, 512, 0);
  k_xw1<<<2048, 256, 0, stream>>>(ne, c1w, xw1f);
  k_split_t<<<dim3(16, 32), dim3(32, 8), 0, stream>>>(xw1f, xw1t, 512, 1024, 1024, 0);
  k_deg_init<<<256, 256, 0, stream>>>(deg);        // deg fused into topk

  // ---- MLP + topk, NCH row-chunks of CH (8-phase 256^2 GEMMs) ----
  for (int c = 0; c < NCH; ++c) {
    int r0 = c * CH;
    k_xcat<<<(CH * 352) / 256, 256, 0, stream>>>(qe, probs, bbox, Xcat, r0, CH * 352);
    k_gemm8<3><<<(CH / 256) * 4, 512, 0, stream>>>(Xcat, W1cat, Hcat2, b1, nullptr,
                                                   CH, 1024, 1088, 704);
    k_gemm8<2><<<(CH / 256) * 4, 512, 0, stream>>>(Hcat2, W2cat, adjf, b2, nullptr,
                                                   CH, 1024, 3072, 2048);
    k_topk<<<CH / 4, 256, 0, stream>>>(adjf, vals, idxo, deg, r0);
  }

  k_dinv<<<256, 256, 0, stream>>>(deg, dinv);

  // ---- GCN, 4 groups of 16 batches; dr folded into Wd columns ----
  for (int g = 0; g < 4; ++g) {
    const float* dg = dinv + g * 16384;
    hipMemsetAsync(Wd, 0, (size_t)33554432, stream);
    k_self<<<64, 256, 0, stream>>>(dinv, Wd, g);
    k_edge<<<2048, 256, 0, stream>>>(vals, idxo, dinv, Wd, g);
    // h1 = (Wd @ xw1) * dinv_c + c1b -> fp16 (16384 x 512), legacy full-grid (512 wgs)
    k_gemm<4, 0><<<dim3(512, 1), 256, 0, stream>>>(Wd, xw1t, h1, c1b, dg,
                                                   16384, 512, 1024, 1024, 4, 0, 0, 0);
    k_bnpart<<<dim3(16, 8), 512, 0, stream>>>(h1, bnp);
    k_bnfin<<<32, 256, 0, stream>>>(bnp, mu, rstd);
    k_bnapply<<<4096, 256, 0, stream>>>(h1, mu, rstd, gamma, beta);
    // xw2t[bl] = (hb @ conv2_w)^T   (16 x 256 x 1024) fp16
    k_gemm<1, 0><<<dim3(256, 1), 256, 0, stream>>>(h1, c2wt, xw2t, nullptr, nullptr,
                                                   16384, 256, 512, 512, 2, 0, 0, 0);
    // out[g*16+bl] = dinv_c * (Wd[bl] @ xw2[bl]) + c2b   fp32 -> d_out
    k_gemm<2, 0><<<dim3(16, 16), 256, 0, stream>>>(Wd, xw2t,
                                                   (float*)d_out + (size_t)g * 16 * 262144,
                                                   c2b, dg, 1024, 256, 1024, 1024, 2,
                                                   1048576LL, 262144LL, 262144LL);
  }
}

// Round 15
// 1402.796 us; speedup vs baseline: 1.0736x; 1.0736x over previous
//
#include <hip/hip_runtime.h>
#include <stdint.h>

typedef float f32x4 __attribute__((ext_vector_type(4)));
typedef _Float16 h16x8 __attribute__((ext_vector_type(8)));
typedef _Float16 h16;
typedef unsigned short u16;

// ---------------- prep kernels ----------------

// LDS-tiled transpose(+optional split3): out (Cn x ostride) from in (Ck x Cn) fp32
__global__ void k_split_t(const float* __restrict__ in, h16* __restrict__ out,
                          int Cn, int Ck, int ostride, int doSplit) {
  __shared__ float t[32][33];
  int n0 = blockIdx.x * 32, k0 = blockIdx.y * 32;
  int tx = threadIdx.x, ty = threadIdx.y;
#pragma unroll
  for (int i = 0; i < 4; ++i)
    t[ty + i * 8][tx] = in[(size_t)(k0 + ty + i * 8) * Cn + n0 + tx];
  __syncthreads();
#pragma unroll
  for (int i = 0; i < 4; ++i) {
    int n = n0 + ty + i * 8, k = k0 + tx;
    float v = t[tx][ty + i * 8];
    h16 h = (h16)v;
    size_t base = (size_t)n * ostride + k;
    out[base] = h;
    if (doSplit) {
      out[base + Ck] = h;
      out[base + 2 * Ck] = (h16)(v - (float)h);
    }
  }
}

// Xcat chunk (CH x 704): [Xh | Xl] for rows [r0, r0+CH)
__global__ void k_xcat(const float* __restrict__ qe, const float* __restrict__ probs,
                       const float* __restrict__ bbox, h16* __restrict__ x, int r0, int n) {
  int i = blockIdx.x * 256 + threadIdx.x;
  if (i >= n) return;
  int rl = i / 352, k = i - rl * 352;
  int R = r0 + rl;
  int nn = R & 1023;
  float v;
  if (k < 256)      v = qe[nn * 256 + k];
  else if (k < 348) v = probs[(size_t)R * 92 + (k - 256)];
  else              v = bbox[(size_t)R * 4 + (k - 348)];
  h16 h = (h16)v;
  h16 l = (h16)(v - (float)h);
  size_t base = (size_t)rl * 704;
  x[base + k] = h; x[base + 352 + k] = l;
}

// xw1f = node_emb @ conv1_w  in fp32 (1024 x 512)
__global__ void k_xw1(const float* __restrict__ ne, const float* __restrict__ c1w,
                      float* __restrict__ xw1f) {
  int r = blockIdx.x >> 1;
  int d = (blockIdx.x & 1) * 256 + threadIdx.x;
  float s = 0.0f;
  for (int k = 0; k < 256; ++k) s += ne[r * 256 + k] * c1w[k * 512 + d];
  xw1f[r * 512 + d] = s;
}

// ---------------- 8-phase 256x256 fp16 MFMA GEMM (BK=64, swizzled LDS, counted vmcnt) ----
// A: (M x AK) row-major fp16; logical K may exceed AK: tiles with base >= AK wrap to base-AK.
// B: (N x K) row-major fp16 (transposed operand). M%256==0, N%256==0, K%64==0.
// MODE 2: fp32 out = acc + bias
// MODE 3: relu(acc+bias) split2 fp16 out (row stride 2N): [c]=hi, [N+c]=lo
// MODE 4: fp16 out row-major = acc*rscale[r] + bias

template<int MODE>
__global__ __launch_bounds__(512, 2)
void k_gemm8(const h16* __restrict__ A, const h16* __restrict__ B, void* __restrict__ Cptr,
             const float* __restrict__ bias, const float* __restrict__ rscale,
             int M, int N, int K, int AK) {
  __shared__ __align__(16) char lds[131072];   // A: [2][256 rows][128B] @0 ; B same @65536
  const int tid = threadIdx.x;
  const int lane = tid & 63, wid = tid >> 6;
  const int wr = wid >> 2, wc = wid & 3;       // 2 x 4 waves, wave tile 128x64

  const int gx = N >> 8;
  const int nwg = gridDim.x, wg = blockIdx.x;
  const int q8 = nwg >> 3, r8 = nwg & 7, xcd = wg & 7, lo = wg >> 3;
  const int swz = (xcd < r8 ? xcd * (q8 + 1) : r8 * (q8 + 1) + (xcd - r8) * q8) + lo;
  const int bx = swz % gx, by = swz / gx;

  const int nt = K >> 6;
  const int srow = tid >> 3, s8 = tid & 7;

  char* ldsA = (char*)lds;
  char* ldsB = (char*)lds + 65536;

  auto stage = [&](const h16* __restrict__ Mat, int rowStride, int tileRowBase,
                   char* ldsBase, int buf, int half, int kbase) {
#pragma unroll
    for (int j = 0; j < 2; ++j) {
      int rl = half * 128 + srow + j * 64;
      int gcol = kbase + ((s8 ^ (rl & 7)) << 3);
      const char* src = (const char*)(Mat + (size_t)(tileRowBase + rl) * rowStride + gcol);
      char* dst = ldsBase + buf * 32768 + half * 16384 + j * 8192 + tid * 16;
      __builtin_amdgcn_global_load_lds((const __attribute__((address_space(1))) void*)src,
                                       (__attribute__((address_space(3))) void*)dst, 16, 0, 0);
    }
  };

  f32x4 acc[8][4] = {};
  h16x8 bfr[4][2];

  auto rdA = [&](int buf, int mf, int ks) -> h16x8 {
    int row = wr * 128 + mf * 16 + (lane & 15);
    int cb = ((ks << 6) + ((lane >> 4) << 4)) ^ ((row & 7) << 4);
    return *(const h16x8*)(ldsA + buf * 32768 + row * 128 + cb);
  };
  auto rdB = [&](int buf, int nf, int ks) -> h16x8 {
    int row = wc * 64 + nf * 16 + (lane & 15);
    int cb = ((ks << 6) + ((lane >> 4) << 4)) ^ ((row & 7) << 4);
    return *(const h16x8*)(ldsB + buf * 32768 + row * 128 + cb);
  };

#define BARRIER() do { asm volatile("" ::: "memory"); \
  __builtin_amdgcn_s_barrier(); asm volatile("" ::: "memory"); } while (0)

#define MFMA16(q, af)                                                          \
  __builtin_amdgcn_s_setprio(1);                                               \
  _Pragma("unroll") for (int m2 = 0; m2 < 2; ++m2)                             \
  _Pragma("unroll") for (int nf = 0; nf < 4; ++nf)                             \
  _Pragma("unroll") for (int ks = 0; ks < 2; ++ks)                             \
    acc[(q) * 2 + m2][nf] = __builtin_amdgcn_mfma_f32_16x16x32_f16(            \
        af[m2][ks], bfr[nf][ks], acc[(q) * 2 + m2][nf], 0, 0, 0);              \
  __builtin_amdgcn_s_setprio(0);

  const int aRow = by * 256, bRow = bx * 256;

  stage(A, AK, aRow, ldsA, 0, 0, 0);
  stage(A, AK, aRow, ldsA, 0, 1, 0);
  stage(B, K, bRow, ldsB, 0, 0, 0);
  stage(B, K, bRow, ldsB, 0, 1, 0);
  stage(B, K, bRow, ldsB, 1, 0, 64);
  stage(B, K, bRow, ldsB, 1, 1, 64);
  asm volatile("s_waitcnt vmcnt(4)" ::: "memory");
  BARRIER();

  for (int T = 0; T < nt; ++T) {
    const int p = T & 1;
    const int tkA = (T + 1) << 6;
    const int aA = (tkA < AK) ? tkA : tkA - AK;
    const int tkB = (T + 2) << 6;
    const bool sA = (T + 1) < nt, sB = (T + 2) < nt;

    {
#pragma unroll
      for (int nf = 0; nf < 4; ++nf)
#pragma unroll
        for (int ks = 0; ks < 2; ++ks) bfr[nf][ks] = rdB(p, nf, ks);
      h16x8 af[2][2];
#pragma unroll
      for (int m2 = 0; m2 < 2; ++m2)
#pragma unroll
        for (int ks = 0; ks < 2; ++ks) af[m2][ks] = rdA(p, m2, ks);
      if (sA) stage(A, AK, aRow, ldsA, p ^ 1, 0, aA);
      BARRIER();
      MFMA16(0, af)
      BARRIER();
    }
    {
      h16x8 af[2][2];
#pragma unroll
      for (int m2 = 0; m2 < 2; ++m2)
#pragma unroll
        for (int ks = 0; ks < 2; ++ks) af[m2][ks] = rdA(p, 2 + m2, ks);
      if (sA) stage(A, AK, aRow, ldsA, p ^ 1, 1, aA);
      BARRIER();
      MFMA16(1, af)
      BARRIER();
    }
    {
      h16x8 af[2][2];
#pragma unroll
      for (int m2 = 0; m2 < 2; ++m2)
#pragma unroll
        for (int ks = 0; ks < 2; ++ks) af[m2][ks] = rdA(p, 4 + m2, ks);
      if (sB) stage(B, K, bRow, ldsB, p, 0, tkB);
      BARRIER();
      MFMA16(2, af)
      BARRIER();
    }
    {
      h16x8 af[2][2];
#pragma unroll
      for (int m2 = 0; m2 < 2; ++m2)
#pragma unroll
        for (int ks = 0; ks < 2; ++ks) af[m2][ks] = rdA(p, 6 + m2, ks);
      if (sB) stage(B, K, bRow, ldsB, p, 1, tkB);
      BARRIER();
      MFMA16(3, af)
      if (sB) { asm volatile("s_waitcnt vmcnt(4)" ::: "memory"); }
      else    { asm volatile("s_waitcnt vmcnt(0)" ::: "memory"); }
      BARRIER();
    }
  }

  const int tM = by * 256 + wr * 128, tN = bx * 256 + wc * 64;
#pragma unroll
  for (int mf = 0; mf < 8; ++mf) {
#pragma unroll
    for (int nf = 0; nf < 4; ++nf) {
      int c = tN + nf * 16 + (lane & 15);
      float bvl = bias[c];
#pragma unroll
      for (int i = 0; i < 4; ++i) {
        int r = tM + mf * 16 + (lane >> 4) * 4 + i;
        float v = acc[mf][nf][i];
        if (MODE == 4) v = v * rscale[r] + bvl;
        else v += bvl;
        if (MODE == 2) {
          ((float*)Cptr)[(size_t)r * N + c] = v;
        } else if (MODE == 4) {
          ((h16*)Cptr)[(size_t)r * N + c] = (h16)v;
        } else {                       // MODE 3: relu + split2, row stride 2N
          v = fmaxf(v, 0.0f);
          h16 h = (h16)v;
          h16 l = (h16)(v - (float)h);
          size_t o = (size_t)r * (2 * N) + c;
          ((h16*)Cptr)[o] = h;
          ((h16*)Cptr)[o + N] = l;
        }
      }
    }
  }
#undef BARRIER
#undef MFMA16
}

// ---------------- legacy 128x128 GEMM (GCN tail) ----------------
// MODE 1: fp16 out, per-1024-row-batch transposed; MODE 2: fp32 out

template<int MODE, int RELU>
__global__ __launch_bounds__(256)
void k_gemm(const h16* __restrict__ A, const h16* __restrict__ B, void* __restrict__ Cptr,
            const float* __restrict__ bias, const float* __restrict__ rscale,
            int M, int N, int K, int AK, int gx,
            long long sA, long long sB, long long sC) {
  __shared__ __align__(16) h16 As[128 * 32];
  __shared__ __align__(16) h16 Bs[128 * 32];
  const int tid = threadIdx.x;
  const int wid = tid >> 6, lane = tid & 63;
  const int wr = wid >> 1, wc = wid & 1;
  const int bz = blockIdx.y;

  const int nwg = gridDim.x, wg = blockIdx.x;
  const int q = nwg >> 3, r8 = nwg & 7, xcd = wg & 7, lo = wg >> 3;
  const int swz = (xcd < r8 ? xcd * (q + 1) : r8 * (q + 1) + (xcd - r8) * q) + lo;
  const int bx = swz % gx, by = swz / gx;

  const char* gA = (const char*)(A + (size_t)bz * sA + (size_t)by * 128 * AK +
                                 (size_t)(tid >> 2) * AK) + (tid & 3) * 16;
  const char* gB = (const char*)(B + (size_t)bz * sB + (size_t)bx * 128 * K +
                                 (size_t)(tid >> 2) * K) + (tid & 3) * 16;
  char* lAs = (char*)As + wid * 1024;
  char* lBs = (char*)Bs + wid * 1024;
  const long long rowStepA = (long long)64 * AK * 2;
  const long long rowStepB = (long long)64 * K * 2;

  f32x4 acc[4][4] = {};
  const int aoff = (wr * 64 + (lane & 15)) * 32 + (lane >> 4) * 8;
  const int boff = (wc * 64 + (lane & 15)) * 32 + (lane >> 4) * 8;

  for (int kt = 0; kt < K; kt += 32) {
    const int akt = (kt < AK) ? kt : kt - AK;
    __syncthreads();
#pragma unroll
    for (int j = 0; j < 2; ++j) {
      __builtin_amdgcn_global_load_lds(
          (const __attribute__((address_space(1))) void*)(gA + j * rowStepA + (size_t)akt * 2),
          (__attribute__((address_space(3))) void*)(lAs + j * 4096), 16, 0, 0);
      __builtin_amdgcn_global_load_lds(
          (const __attribute__((address_space(1))) void*)(gB + j * rowStepB + (size_t)kt * 2),
          (__attribute__((address_space(3))) void*)(lBs + j * 4096), 16, 0, 0);
    }
    asm volatile("s_waitcnt vmcnt(0)" ::: "memory");
    __syncthreads();

    h16x8 af[4], bv[4];
#pragma unroll
    for (int m = 0; m < 4; ++m) af[m] = *(const h16x8*)(As + aoff + m * 512);
#pragma unroll
    for (int n = 0; n < 4; ++n) bv[n] = *(const h16x8*)(Bs + boff + n * 512);
#pragma unroll
    for (int m = 0; m < 4; ++m)
#pragma unroll
      for (int n = 0; n < 4; ++n)
        acc[m][n] = __builtin_amdgcn_mfma_f32_16x16x32_f16(af[m], bv[n], acc[m][n], 0, 0, 0);
  }

  const int tM = by * 128 + wr * 64, tN = bx * 128 + wc * 64;
#pragma unroll
  for (int m = 0; m < 4; ++m) {
#pragma unroll
    for (int n = 0; n < 4; ++n) {
      int c = tN + n * 16 + (lane & 15);
      float bvl = bias ? bias[c] : 0.0f;
#pragma unroll
      for (int i = 0; i < 4; ++i) {
        int r = tM + m * 16 + (lane >> 4) * 4 + i;
        float v = acc[m][n][i];
        if (rscale) v *= rscale[bz * 1024 + r];
        v += bvl;
        if (RELU) v = fmaxf(v, 0.0f);
        if (MODE == 1) {
          size_t o = ((size_t)(r >> 10) * N + c) * 1024 + (r & 1023);
          ((h16*)Cptr)[o] = (h16)v;
        } else if (MODE == 2) {
          size_t o = (size_t)bz * sC + (size_t)r * N + c;
          ((float*)Cptr)[o] = v;
        }
      }
    }
  }
}

// ---------------- top-k via 4-level (full 32-bit) radix select, one wave per row ----

__global__ void k_topk(const float* __restrict__ adj, float* __restrict__ vals,
                       u16* __restrict__ idxo, int r0) {
  __shared__ unsigned binsAll[4][256];
  const int wv = threadIdx.x >> 6, lane = threadIdx.x & 63;
  unsigned* bins = binsAll[wv];
  const int rl = blockIdx.x * 4 + wv;

  float v[16]; unsigned key[16];
  const float4* rp = (const float4*)(adj + (size_t)rl * 1024 + lane * 16);
#pragma unroll
  for (int q = 0; q < 4; ++q) {
    float4 t = rp[q];
    v[4 * q] = t.x; v[4 * q + 1] = t.y; v[4 * q + 2] = t.z; v[4 * q + 3] = t.w;
  }
#pragma unroll
  for (int j = 0; j < 16; ++j) {
    unsigned b = __float_as_uint(v[j]);
    key[j] = b ^ (unsigned)(((int)b >> 31) | (int)0x80000000);
  }

  unsigned pfx = 0; int need = 32;
#pragma unroll
  for (int lvl = 0; lvl < 4; ++lvl) {
    const int shift = 24 - lvl * 8;
    bins[lane] = 0; bins[lane + 64] = 0; bins[lane + 128] = 0; bins[lane + 192] = 0;
    __syncthreads();
#pragma unroll
    for (int j = 0; j < 16; ++j) {
      bool cand = (lvl == 0) || ((key[j] >> (shift + 8)) == pfx);
      if (cand) atomicAdd(&bins[(key[j] >> shift) & 255u], 1u);
    }
    __syncthreads();
    int c0 = (int)bins[lane * 4 + 0], c1 = (int)bins[lane * 4 + 1],
        c2 = (int)bins[lane * 4 + 2], c3 = (int)bins[lane * 4 + 3];
    int s = c0 + c1 + c2 + c3;
    int inc = s;
#pragma unroll
    for (int off = 1; off < 64; off <<= 1) {
      int t = __shfl_down(inc, off);
      if (lane + off < 64) inc += t;
    }
    int gt3 = inc - s;
    int gt2 = gt3 + c3, gt1 = gt2 + c2, gt0 = gt1 + c1;
    int tloc = -1, gtsel = 0;
    if (gt3 < need && gt3 + c3 >= need) { tloc = lane * 4 + 3; gtsel = gt3; }
    if (gt2 < need && gt2 + c2 >= need) { tloc = lane * 4 + 2; gtsel = gt2; }
    if (gt1 < need && gt1 + c1 >= need) { tloc = lane * 4 + 1; gtsel = gt1; }
    if (gt0 < need && gt0 + c0 >= need) { tloc = lane * 4 + 0; gtsel = gt0; }
    unsigned long long bal = __ballot(tloc >= 0);
    int src = __ffsll(bal) - 1;
    int t   = __shfl(tloc, src);
    int gtv = __shfl(gtsel, src);
    pfx = (pfx << 8) | (unsigned)t;
    need -= gtv;
    __syncthreads();
  }

  // pfx is now the full 32-bit key of the 32nd element (the threshold key).
  unsigned sureMask = 0, tieMask = 0;
#pragma unroll
  for (int j = 0; j < 16; ++j) {
    if (key[j] > pfx) sureMask |= (1u << j);
    else if (key[j] == pfx) tieMask |= (1u << j);
  }
  int cs = __popc(sureMask), ct = __popc(tieMask);
  int incS = cs, incT = ct;
#pragma unroll
  for (int off = 1; off < 64; off <<= 1) {
    int a = __shfl_up(incS, off);
    int b2 = __shfl_up(incT, off);
    if (lane >= off) { incS += a; incT += b2; }
  }
  int baseS = incS - cs, baseT = incT - ct;
  int totalS = __shfl(incS, 63);
  size_t obase = ((size_t)(r0 + rl)) * 32;
  int o = baseS;
#pragma unroll
  for (int j = 0; j < 16; ++j)
    if (sureMask & (1u << j)) {
      vals[obase + o] = v[j];
      idxo[obase + o] = (u16)(lane * 16 + j);
      ++o;
    }
  int o2 = totalS + baseT;
#pragma unroll
  for (int j = 0; j < 16; ++j)
    if (tieMask & (1u << j)) {
      if (o2 < 32) { vals[obase + o2] = v[j]; idxo[obase + o2] = (u16)(lane * 16 + j); }
      ++o2;
    }
}

// ---------------- degree / dinv / W build (dr folded into W columns) ----------------

__global__ void k_deg_init(float* deg) {
  int i = blockIdx.x * 256 + threadIdx.x;
  if (i < 65536) deg[i] = 1.0f;
}

__global__ void k_deg_acc(const float* __restrict__ vals, const u16* __restrict__ idxo,
                          float* __restrict__ deg) {
  int e = blockIdx.x * 256 + threadIdx.x;
  int b = e >> 15;
  atomicAdd(&deg[b * 1024 + (int)idxo[e]], vals[e]);
}

__global__ void k_dinv(const float* __restrict__ deg, float* __restrict__ dinv) {
  int i = blockIdx.x * 256 + threadIdx.x;
  if (i >= 65536) return;
  float d = deg[i];
  float r = 1.0f / sqrtf(d);
  if (isinf(r)) r = 0.0f;
  dinv[i] = r;
}

__global__ void k_self(const float* __restrict__ dinv, h16* __restrict__ Wd, int g) {
  int i = blockIdx.x * 256 + threadIdx.x;
  if (i >= 16384) return;
  int bl = i >> 10, c = i & 1023;
  Wd[((size_t)bl << 20) + (size_t)c * 1024 + c] = (h16)dinv[g * 16384 + i];
}

__global__ void k_edge(const float* __restrict__ vals, const u16* __restrict__ idxo,
                       const float* __restrict__ dinv, h16* __restrict__ Wd, int g) {
  int e = blockIdx.x * 256 + threadIdx.x;
  if (e >= 524288) return;
  int bl = e >> 15;
  int r = (e >> 5) & 1023;
  size_t E = (size_t)g * 524288 + e;
  int c = (int)idxo[E];
  float w = vals[E] * dinv[g * 16384 + (bl << 10) + r];
  size_t o = ((size_t)bl << 20) + (size_t)c * 1024 + r;
  Wd[o] = (h16)((float)Wd[o] + w);
}

// ---------------- batchnorm (fp16 h1, in-place apply), two-stage ----------------

__global__ void k_bnpart(const h16* __restrict__ h1, float2* __restrict__ part) {
  int b = blockIdx.x, seg = blockIdx.y, d = threadIdx.x;
  size_t base = ((size_t)(b * 1024 + seg * 128)) * 512 + d;
  float s = 0.0f, ss = 0.0f;
  for (int n = 0; n < 128; ++n) {
    float h = (float)h1[base + (size_t)n * 512];
    s += h; ss += h * h;
  }
  part[(size_t)(b * 8 + seg) * 512 + d] = make_float2(s, ss);
}

__global__ void k_bnfin(const float2* __restrict__ part, float* __restrict__ mu,
                        float* __restrict__ rstd) {
  int i = blockIdx.x * 256 + threadIdx.x;
  if (i >= 8192) return;
  int b = i >> 9, d = i & 511;
  float s = 0.0f, ss = 0.0f;
  for (int seg = 0; seg < 8; ++seg) {
    float2 t = part[(size_t)(b * 8 + seg) * 512 + d];
    s += t.x; ss += t.y;
  }
  float m = s * (1.0f / 1024.0f);
  float var = ss * (1.0f / 1024.0f) - m * m;
  mu[b * 512 + d] = m;
  rstd[b * 512 + d] = 1.0f / sqrtf(var + 1e-5f);
}

// vectorized: 8 fp16 per thread (d-contiguous)
__global__ void k_bnapply(h16* __restrict__ h1, const float* __restrict__ mu,
                          const float* __restrict__ rstd, const float* __restrict__ gamma,
                          const float* __restrict__ beta) {
  int i = blockIdx.x * 256 + threadIdx.x;       // 16*1024*512/8 = 1,048,576 threads
  if (i >= 1048576) return;
  int i8 = i * 8;
  int d0 = i8 & 511;
  int b = i8 >> 19;
  h16x8 hv = *(const h16x8*)(h1 + i8);
  h16x8 ov;
#pragma unroll
  for (int j = 0; j < 8; ++j) {
    int d = d0 + j;
    float y = ((float)hv[j] - mu[b * 512 + d]) * rstd[b * 512 + d] * gamma[d] + beta[d];
    ov[j] = (h16)fmaxf(y, 0.0f);
  }
  *(h16x8*)(h1 + i8) = ov;
}

// ---------------- launch ----------------

extern "C" void kernel_launch(void* const* d_in, const int* in_sizes, int n_in,
                              void* d_out, int out_size, void* d_ws, size_t ws_size,
                              hipStream_t stream) {
  const float* probs = (const float*)d_in[0];
  const float* bbox  = (const float*)d_in[1];
  const float* qe    = (const float*)d_in[2];
  const float* ne    = (const float*)d_in[3];
  const float* w1    = (const float*)d_in[4];
  const float* b1    = (const float*)d_in[5];
  const float* w2    = (const float*)d_in[6];
  const float* b2    = (const float*)d_in[7];
  const float* c1w   = (const float*)d_in[8];
  const float* c1b   = (const float*)d_in[9];
  const float* c2w   = (const float*)d_in[10];
  const float* c2b   = (const float*)d_in[11];
  const float* gamma = (const float*)d_in[12];
  const float* beta  = (const float*)d_in[13];

  if (ws_size < 82444288ULL) return;               // minimum layout
  const bool big = ws_size >= 115998720ULL;        // 16K-row MLP chunks if room
  const int CH = big ? 16384 : 8192;
  const int NCH = 65536 / CH;

  char* p = (char*)d_ws;
  h16* W1cat = (h16*)p; p += (size_t)1024 * 1088 * 2;   //  K padded to 1088
  h16* W2cat = (h16*)p; p += (size_t)1024 * 3072 * 2;
  h16* c2wt  = (h16*)p; p += (size_t)256 * 512 * 2;
  float* xw1f = (float*)p; p += (size_t)1024 * 512 * 4;
  h16*  xw1t = (h16*)p;  p += (size_t)512 * 1024 * 2;
  float* vals = (float*)p; p += (size_t)2097152 * 4;
  u16*   idxo = (u16*)p;   p += (size_t)2097152 * 2;
  float* deg  = (float*)p; p += (size_t)65536 * 4;
  float* dinv = (float*)p; p += (size_t)65536 * 4;
  float* mu   = (float*)p; p += (size_t)64 * 512 * 4;
  float* rstd = (float*)p; p += (size_t)64 * 512 * 4;
  float2* bnp = (float2*)p; p += (size_t)16 * 8 * 512 * 8;
  char* R1 = p;
  // MLP phase: Xcat (CH x 704 fp16) | Hcat2 (CH x 2048 fp16)
  h16* Xcat  = (h16*)R1;
  h16* Hcat2 = (h16*)(R1 + (size_t)CH * 704 * 2);
  // GCN phase: Wd(32MB) | h1(16MB) | xw2t(8MB)
  h16* Wd   = (h16*)R1;
  h16* h1   = (h16*)(R1 + 33554432);
  h16* xw2t = (h16*)(R1 + 50331648);
  float* adjf = (float*)d_out;                     // CH x 1024 fp32 chunk

  // ---- weight prep ----
  hipMemsetAsync(W1cat, 0, (size_t)1024 * 1088 * 2, stream);
  k_split_t<<<dim3(32, 11), dim3(32, 8), 0, stream>>>(w1, W1cat, 1024, 352, 1088, 1);
  k_split_t<<<dim3(32, 32), dim3(32, 8), 0, stream>>>(w2, W2cat, 1024, 1024, 3072, 1);
  k_split_t<<<dim3(8, 16), dim3(32, 8), 0, stream>>>(c2w, c2wt, 256, 512, 512, 0);
  k_xw1<<<2048, 256, 0, stream>>>(ne, c1w, xw1f);
  k_split_t<<<dim3(16, 32), dim3(32, 8), 0, stream>>>(xw1f, xw1t, 512, 1024, 1024, 0);

  // ---- MLP + topk, NCH row-chunks of CH (8-phase 256^2 GEMMs) ----
  for (int c = 0; c < NCH; ++c) {
    int r0 = c * CH;
    k_xcat<<<(CH * 352) / 256, 256, 0, stream>>>(qe, probs, bbox, Xcat, r0, CH * 352);
    k_gemm8<3><<<(CH / 256) * 4, 512, 0, stream>>>(Xcat, W1cat, Hcat2, b1, nullptr,
                                                   CH, 1024, 1088, 704);
    k_gemm8<2><<<(CH / 256) * 4, 512, 0, stream>>>(Hcat2, W2cat, adjf, b2, nullptr,
                                                   CH, 1024, 3072, 2048);
    k_topk<<<CH / 4, 256, 0, stream>>>(adjf, vals, idxo, r0);
  }

  // ---- degrees ----
  k_deg_init<<<256, 256, 0, stream>>>(deg);
  k_deg_acc<<<8192, 256, 0, stream>>>(vals, idxo, deg);
  k_dinv<<<256, 256, 0, stream>>>(deg, dinv);

  // ---- GCN, 4 groups of 16 batches; dr folded into Wd columns ----
  for (int g = 0; g < 4; ++g) {
    const float* dg = dinv + g * 16384;
    hipMemsetAsync(Wd, 0, (size_t)33554432, stream);
    k_self<<<64, 256, 0, stream>>>(dinv, Wd, g);
    k_edge<<<2048, 256, 0, stream>>>(vals, idxo, dinv, Wd, g);
    // h1 = (Wd @ xw1) * dinv_c + c1b  -> fp16 (16384 x 512), flat 8-phase GEMM
    k_gemm8<4><<<128, 512, 0, stream>>>(Wd, xw1t, h1, c1b, dg, 16384, 512, 1024, 1024);
    k_bnpart<<<dim3(16, 8), 512, 0, stream>>>(h1, bnp);
    k_bnfin<<<32, 256, 0, stream>>>(bnp, mu, rstd);
    k_bnapply<<<4096, 256, 0, stream>>>(h1, mu, rstd, gamma, beta);
    // xw2t[bl] = (hb @ conv2_w)^T   (16 x 256 x 1024) fp16
    k_gemm<1, 0><<<dim3(256, 1), 256, 0, stream>>>(h1, c2wt, xw2t, nullptr, nullptr,
                                                   16384, 256, 512, 512, 2, 0, 0, 0);
    // out[g*16+bl] = dinv_c * (Wd[bl] @ xw2[bl]) + c2b   fp32 -> d_out
    k_gemm<2, 0><<<dim3(16, 16), 256, 0, stream>>>(Wd, xw2t,
                                                   (float*)d_out + (size_t)g * 16 * 262144,
                                                   c2b, dg, 1024, 256, 1024, 1024, 2,
                                                   1048576LL, 262144LL, 262144LL);
  }
}